// Round 1
// baseline (104.847 us; speedup 1.0000x reference)
//
#include <hip/hip_runtime.h>
#include <math.h>

#define C 256
#define H 40
#define W 40
#define NROI 64
#define PH 7
#define PW 7
#define HW (H * W)

// Kernel 1: s[p] = sum_c fm[c][p]; smax = max_p s[p] (int-bits atomicMax, s>0).
__global__ __launch_bounds__(64) void saliency_kernel(
    const float* __restrict__ fm, float* __restrict__ s_out,
    int* __restrict__ smax_bits) {
  int p = blockIdx.x * blockDim.x + threadIdx.x;  // exactly 1600 threads
  float acc = 0.0f;
#pragma unroll 8
  for (int c = 0; c < C; ++c) acc += fm[c * HW + p];  // coalesced across lanes
  s_out[p] = acc;
  float m = acc;
#pragma unroll
  for (int off = 32; off > 0; off >>= 1) m = fmaxf(m, __shfl_down(m, off));
  if ((threadIdx.x & 63) == 0) atomicMax(smax_bits, __float_as_int(m));
}

// Kernel 2: one thread per output element (n,c,ph,pw).
__global__ __launch_bounds__(256) void pool_kernel(
    const float* __restrict__ fm, const float* __restrict__ rois1,
    const float* __restrict__ rois2, const float* __restrict__ sal,
    const int* __restrict__ smax_bits, float* __restrict__ out) {
  int idx = blockIdx.x * blockDim.x + threadIdx.x;
  int pw = idx % PW;
  int t = idx / PW;
  int ph = t % PH;
  t /= PH;
  int c = t & (C - 1);
  int n = t >> 8;

  const float* r1 = rois1 + n * 5;
  const float* r2 = rois2 + n * 5;
  // jnp.round = round-half-to-even = rintf under default rounding mode.
  int x1a = min((int)rintf(r1[1] * 0.0625f), W - 1);
  int y1a = min((int)rintf(r1[2] * 0.0625f), H - 1);
  int x2a = min((int)rintf(r1[3] * 0.0625f), W - 1);
  int y2a = min((int)rintf(r1[4] * 0.0625f), H - 1);
  int x1b = min((int)rintf(r2[1] * 0.0625f), W - 1);
  int y1b = min((int)rintf(r2[2] * 0.0625f), H - 1);
  int x2b = min((int)rintf(r2[3] * 0.0625f), W - 1);
  int y2b = min((int)rintf(r2[4] * 0.0625f), H - 1);

  int ux1 = min(x1a, x1b), uy1 = min(y1a, y1b);
  int ux2 = max(x2a, x2b), uy2 = max(y2a, y2b);
  int hb = uy2 - uy1 + 1, wb = ux2 - ux1 + 1;

  // AdaptiveMaxPool bin: [lo + floor(i*hb/P), lo + ceil((i+1)*hb/P))
  int ys0 = uy1 + (ph * hb) / PH;
  int ys1 = uy1 + ((ph + 1) * hb + PH - 1) / PH;
  int xs0 = ux1 + (pw * wb) / PW;
  int xs1 = ux1 + ((pw + 1) * wb + PW - 1) / PW;

  float inv = 1.0f / __int_as_float(*smax_bits);
  const float* fmc = fm + c * HW;
  float best = -INFINITY;
  for (int y = ys0; y < ys1; ++y) {
    bool ay = (y >= y1a) & (y <= y2a);
    bool by = (y >= y1b) & (y <= y2b);
    int row = y * W;
    for (int x = xs0; x < xs1; ++x) {
      bool ins = (ay & (x >= x1a) & (x <= x2a)) |
                 (by & (x >= x1b) & (x <= x2b));
      float q = sal[row + x] * inv;   // (s/smax)
      q = q * q;
      q = q * q;                      // ^4
      float m = ins ? 1.0f : (0.5f + 0.4f * q);
      best = fmaxf(best, fmc[row + x] * m);
    }
  }
  out[idx] = best;
}

extern "C" void kernel_launch(void* const* d_in, const int* in_sizes, int n_in,
                              void* d_out, int out_size, void* d_ws,
                              size_t ws_size, hipStream_t stream) {
  const float* fm = (const float*)d_in[0];
  const float* r1 = (const float*)d_in[1];
  const float* r2 = (const float*)d_in[2];
  float* out = (float*)d_out;
  float* sal = (float*)d_ws;                                // 1600 floats
  int* smax_bits = (int*)((char*)d_ws + HW * sizeof(float)); // 1 int

  // Zero smax (and sal, harmlessly): 0 < any positive float as int bits.
  hipMemsetAsync(d_ws, 0, (HW + 1) * sizeof(float), stream);
  saliency_kernel<<<HW / 64, 64, 0, stream>>>(fm, sal, smax_bits);
  pool_kernel<<<(NROI * C * PH * PW) / 256, 256, 0, stream>>>(
      fm, r1, r2, sal, smax_bits, out);
}